// Round 6
// baseline (502.399 us; speedup 1.0000x reference)
//
#include <hip/hip_runtime.h>
#include <math.h>

#define N_NODES 661
#define N_GRAPH 128
#define DEG 8
#define EPG (N_NODES*DEG)          // 5288 edges per graph per matrix
#define NTOT (N_NODES*N_GRAPH)     // 84608 nodes
#define FDIM 64
#define NF ((size_t)NTOT*FDIM)     // elements per [n,64] array
#define OSTR 672                   // padded CSR offsets stride
#define NTILE 22
#define TROWS 31                   // 22*31 = 682 >= 661

using short8  = __attribute__((ext_vector_type(8))) short;
using float4v = __attribute__((ext_vector_type(4))) float;

__device__ __forceinline__ unsigned short f2bf(float x) {
    unsigned int u = __float_as_uint(x);
    unsigned int r = u + 0x7FFFu + ((u >> 16) & 1u);
    return (unsigned short)(r >> 16);
}
__device__ __forceinline__ float bf2f(unsigned short h) {
    return __uint_as_float(((unsigned int)h) << 16);
}

// ---------------------------------------------------------------------------
// Kernel 1 (fused): blocks 0..511 -> per-(graph,matrix) LDS counting sort ->
// CSR; blocks 512..591 -> wtrans (bf16 hi/lo W fragments in MFMA B-layout).
// ---------------------------------------------------------------------------
__global__ __launch_bounds__(256) void csr_build(
    const int* __restrict__ rG, const int* __restrict__ cG, const float* __restrict__ vG,
    const int* __restrict__ rB, const int* __restrict__ cB, const float* __restrict__ vB,
    const int* __restrict__ r1, const int* __restrict__ c1, const float* __restrict__ v1,
    const int* __restrict__ r2, const int* __restrict__ c2, const float* __restrict__ v2,
    const float* __restrict__ W1, const float* __restrict__ W2,
    unsigned short* __restrict__ Wb1h, unsigned short* __restrict__ Wb1l,
    unsigned short* __restrict__ Wb2h, unsigned short* __restrict__ Wb2l,
    int* __restrict__ offs_out, int2* __restrict__ pairs_out)
{
    int bid = blockIdx.x;
    int tid = threadIdx.x;

    if (bid >= 512) {                     // ---- wtrans part ----
        int i = (bid - 512)*256 + tid;    // 0..20479
        int j    = i & 7;
        int lane = (i >> 3) & 63;
        int ot   = (i >> 9) & 3;
        int ks   = i >> 11;
        int k = ks*32 + (lane >> 4)*8 + j;
        int o = ot*16 + (lane & 15);
        float w1 = W1[o*320 + k];
        float w2 = W2[o*320 + k];
        unsigned short h1 = f2bf(w1); Wb1h[i] = h1; Wb1l[i] = f2bf(w1 - bf2f(h1));
        unsigned short h2 = f2bf(w2); Wb2h[i] = h2; Wb2l[i] = f2bf(w2 - bf2f(h2));
        return;
    }

    __shared__ int   scount[N_NODES];
    __shared__ int   soffs[N_NODES+1];
    __shared__ int   scursor[N_NODES];
    __shared__ int   scol[EPG];
    __shared__ float sval[EPG];
    __shared__ int   sscan[256];

    int g = bid & 127;
    int m = bid >> 7;
    const int*   rows = (m==0)?rG:(m==1)?rB:(m==2)?r1:r2;
    const int*   cols = (m==0)?cG:(m==1)?cB:(m==2)?c1:c2;
    const float* vals = (m==0)?vG:(m==1)?vB:(m==2)?v1:v2;

    int ebase = g*EPG;
    int gbase = g*N_NODES;
    int seg = m*N_GRAPH + g;

    for (int i = tid; i < N_NODES; i += 256) scount[i] = 0;
    __syncthreads();
    for (int i = tid; i < EPG; i += 256)
        atomicAdd(&scount[rows[ebase+i] - gbase], 1);
    __syncthreads();

    int c0 = tid*3;
    int ps = 0;
    #pragma unroll
    for (int j = 0; j < 3; ++j) { int i = c0+j; if (i < N_NODES) ps += scount[i]; }
    sscan[tid] = ps;
    __syncthreads();
    #pragma unroll
    for (int d = 1; d < 256; d <<= 1) {
        int v = (tid >= d) ? sscan[tid-d] : 0;
        __syncthreads();
        sscan[tid] += v;
        __syncthreads();
    }
    int run = sscan[tid] - ps;   // exclusive prefix
    #pragma unroll
    for (int j = 0; j < 3; ++j) {
        int i = c0+j;
        if (i < N_NODES) { soffs[i] = run; scursor[i] = run; run += scount[i]; }
    }
    if (tid == 0) soffs[N_NODES] = EPG;
    __syncthreads();

    for (int i = tid; i < EPG; i += 256) {
        int r = rows[ebase+i] - gbase;
        int pos = atomicAdd(&scursor[r], 1);
        scol[pos] = cols[ebase+i];
        sval[pos] = vals[ebase+i];
    }
    __syncthreads();

    for (int i = tid; i <= N_NODES; i += 256)
        offs_out[(size_t)seg*OSTR + i] = soffs[i];
    int2* po = pairs_out + (size_t)seg*EPG;
    for (int i = tid; i < EPG; i += 256)
        po[i] = make_int2(scol[i], __float_as_int(sval[i]));
}

// ---------------------------------------------------------------------------
__device__ __forceinline__ void node_math1(
    float ev, float fv, float gd, float bd, float pd, float qd,
    float eGv, float fGv, float eBv, float fBv,
    float& e3v, float& nev, float& f3v, float& nfv)
{
    float invb = 1.0f/(ev*ev + fv*fv + 0.1f);
    float alpha = (pd*ev + qd*fv)*invb - eGv - fBv;
    float beta  = (qd*ev - pd*fv)*invb + fGv + eBv;
    float invg = 1.0f/(gd*gd + bd*bd);
    e3v = (alpha*gd + beta*bd)*invg;
    f3v = (beta*gd - alpha*bd)*invg;
    float bb1 = eGv - fBv, bb2 = fGv + eBv;
    float vv = ev*ev + fv*fv;
    float P_ = pd - vv*gd, Q_ = qd + vv*bd;
    nev = (P_*bb1 + Q_*bb2)*invg;
    nfv = (P_*bb2 - Q_*bb1)*invg;
}

// ---------------------------------------------------------------------------
// Kernel 2: gather SpMM v2.
// lane = (eh, fp): eh = edge half (2 edges per slot), fp = feature pair
// (float2 per lane). Both matrices of the set processed in merged trips ->
// 32 loads in flight per wave. Epilogue on lanes 0..31 in float2.
// Grid: 5632 = 8 XCD * 16 graphs * 44 (22 tiles x 2 sets).
// ---------------------------------------------------------------------------
__global__ __launch_bounds__(256) void gather_all(
    const float* __restrict__ e, const float* __restrict__ f,
    const float* __restrict__ Gd, const float* __restrict__ Bd,
    const float* __restrict__ Pd, const float* __restrict__ Qd,
    const float* __restrict__ w_ae, const float* __restrict__ w_af,
    const int* __restrict__ offs, const int2* __restrict__ pairs,
    float* __restrict__ arrs, float* __restrict__ partials)
{
    int tid = threadIdx.x, lane = tid & 63, wv = tid >> 6;
    int fp = lane & 31, eh = lane >> 5;
    int bid = blockIdx.x;
    int xcd = bid & 7, loc = bid >> 3;          // loc 0..703
    int g    = xcd*16 + loc/44;
    int sub  = loc % 44;
    int set  = (sub < NTILE) ? 0 : 1;
    int tile = sub - set*NTILE;
    int r0   = tile*TROWS;
    int rlim = min(TROWS, N_NODES - r0);
    int mA = set ? 2 : 0, mB = set ? 3 : 1;

    const int*  poA = offs + (size_t)(mA*N_GRAPH + g)*OSTR;
    const int*  poB = offs + (size_t)(mB*N_GRAPH + g)*OSTR;
    const int2* ppA = pairs + (size_t)(mA*N_GRAPH + g)*EPG;
    const int2* ppB = pairs + (size_t)(mB*N_GRAPH + g)*EPG;

    float pa0 = 0.f, pa1 = 0.f, pa2 = 0.f, pa3 = 0.f;
    float2 wa2, wf2;
    { const float2* p = (const float2*)(w_ae) + fp; wa2 = *p; }
    { const float2* p = (const float2*)(w_af) + fp; wf2 = *p; }

    for (int lr = wv; lr < rlim; lr += 4) {
        int r = r0 + lr;
        int node = g*N_NODES + r;
        int sA = poA[r], tA = poA[r+1];
        int sB = poB[r], tB = poB[r+1];
        int nmax = max(tA - sA, tB - sB);
        int trips = (nmax + 7) >> 3;

        float2 aE = {0.f,0.f}, aF = {0.f,0.f}, bE = {0.f,0.f}, bF = {0.f,0.f};

        for (int it = 0; it < trips; ++it) {
            int baseA = sA + it*8 + eh;
            int baseB = sB + it*8 + eh;
            int2 pA[4], pB[4];
            #pragma unroll
            for (int j = 0; j < 4; ++j) {
                int kA = baseA + 2*j;
                int kB = baseB + 2*j;
                pA[j] = ppA[kA < tA ? kA : 0];
                pB[j] = ppB[kB < tB ? kB : 0];
                if (kA >= tA) pA[j].y = 0;
                if (kB >= tB) pB[j].y = 0;
            }
            float2 evA[4], fvA[4], evB[4], fvB[4];
            #pragma unroll
            for (int j = 0; j < 4; ++j) {
                size_t oA = ((size_t)pA[j].x << 6) + (fp << 1);
                size_t oB = ((size_t)pB[j].x << 6) + (fp << 1);
                evA[j] = *(const float2*)(e + oA);
                fvA[j] = *(const float2*)(f + oA);
                evB[j] = *(const float2*)(e + oB);
                fvB[j] = *(const float2*)(f + oB);
            }
            #pragma unroll
            for (int j = 0; j < 4; ++j) {
                float vA = __int_as_float(pA[j].y);
                float vB = __int_as_float(pB[j].y);
                aE.x = fmaf(vA, evA[j].x, aE.x); aE.y = fmaf(vA, evA[j].y, aE.y);
                aF.x = fmaf(vA, fvA[j].x, aF.x); aF.y = fmaf(vA, fvA[j].y, aF.y);
                bE.x = fmaf(vB, evB[j].x, bE.x); bE.y = fmaf(vB, evB[j].y, bE.y);
                bF.x = fmaf(vB, fvB[j].x, bF.x); bF.y = fmaf(vB, fvB[j].y, bF.y);
            }
        }
        // combine edge halves -> lanes 0..31 hold row sums
        aE.x += __shfl_down(aE.x, 32); aE.y += __shfl_down(aE.y, 32);
        aF.x += __shfl_down(aF.x, 32); aF.y += __shfl_down(aF.y, 32);
        bE.x += __shfl_down(bE.x, 32); bE.y += __shfl_down(bE.y, 32);
        bF.x += __shfl_down(bF.x, 32); bF.y += __shfl_down(bF.y, 32);

        if (eh == 0) {
            size_t idx2 = (size_t)node*FDIM + (fp << 1);
            if (set == 0) {
                float2 ev2 = *(const float2*)(e + idx2);
                float2 fv2 = *(const float2*)(f + idx2);
                float gd = Gd[node], bd = Bd[node], pd = Pd[node], qd = Qd[node];
                float2 e3v, nev, f3v, nfv;
                node_math1(ev2.x, fv2.x, gd, bd, pd, qd, aE.x, aF.x, bE.x, bF.x,
                           e3v.x, nev.x, f3v.x, nfv.x);
                node_math1(ev2.y, fv2.y, gd, bd, pd, qd, aE.y, aF.y, bE.y, bF.y,
                           e3v.y, nev.y, f3v.y, nfv.y);
                *(float2*)(arrs + 0*NF + idx2) = e3v;
                *(float2*)(arrs + 1*NF + idx2) = nev;
                *(float2*)(arrs + 4*NF + idx2) = f3v;
                *(float2*)(arrs + 5*NF + idx2) = nfv;
                pa0 += e3v.x*wa2.x + e3v.y*wa2.y;
                pa1 += nev.x*wa2.x + nev.y*wa2.y;
                pa2 += f3v.x*wf2.x + f3v.y*wf2.y;
                pa3 += nfv.x*wf2.x + nfv.y*wf2.y;
            } else {
                *(float2*)(arrs + 2*NF + idx2) = aE;   // e1
                *(float2*)(arrs + 6*NF + idx2) = aF;   // f1
                *(float2*)(arrs + 3*NF + idx2) = bE;   // e2
                *(float2*)(arrs + 7*NF + idx2) = bF;   // f2
                pa0 += aE.x*wa2.x + aE.y*wa2.y;
                pa1 += bE.x*wa2.x + bE.y*wa2.y;
                pa2 += aF.x*wf2.x + aF.y*wf2.y;
                pa3 += bF.x*wf2.x + bF.y*wf2.y;
            }
        }
    }

    // reduce over lanes 0..31 (tree valid for lane-0 result), then block reduce
    __shared__ float sred[4];
    if (tid < 4) sred[tid] = 0.f;
    __syncthreads();
    #pragma unroll
    for (int off = 16; off > 0; off >>= 1) {
        pa0 += __shfl_down(pa0, off); pa1 += __shfl_down(pa1, off);
        pa2 += __shfl_down(pa2, off); pa3 += __shfl_down(pa3, off);
    }
    if (lane == 0) {
        atomicAdd(&sred[0], pa0); atomicAdd(&sred[1], pa1);
        atomicAdd(&sred[2], pa2); atomicAdd(&sred[3], pa3);
    }
    __syncthreads();
    if (tid == 0) {
        float* pt = partials + ((size_t)g*NTILE + tile)*8;
        if (set == 0) { pt[0] = sred[0]; pt[1] = sred[1]; pt[4] = sred[2]; pt[5] = sred[3]; }
        else          { pt[2] = sred[0]; pt[3] = sred[1]; pt[6] = sred[2]; pt[7] = sred[3]; }
    }
}

// ---------------------------------------------------------------------------
// Kernel 3: finalize attention weights (sum 22 tile-partials, sigmoid, norm)
// ---------------------------------------------------------------------------
__global__ void attn_final(const float* __restrict__ partials,
                           const float* __restrict__ b_ae, const float* __restrict__ b_af,
                           float* __restrict__ att)
{
    int g = threadIdx.x;
    if (g >= N_GRAPH) return;
    float s[8];
    #pragma unroll
    for (int j = 0; j < 8; ++j) {
        float t = 0.f;
        for (int q = 0; q < NTILE; ++q) t += partials[((size_t)g*NTILE + q)*8 + j];
        s[j] = t;
    }
    float ae[4], af[4], se = 1e-4f, sf = 1e-4f;
    float bae = b_ae[0], baf = b_af[0];
    #pragma unroll
    for (int j = 0; j < 4; ++j) {
        float x = s[j]*(1.0f/N_NODES) + bae;
        ae[j] = 1.0f/(1.0f + expf(-x)); se += ae[j];
        float y = s[4+j]*(1.0f/N_NODES) + baf;
        af[j] = 1.0f/(1.0f + expf(-y)); sf += af[j];
    }
    #pragma unroll
    for (int j = 0; j < 4; ++j) {
        att[g*8 + j]     = ae[j]/se;
        att[g*8 + 4 + j] = af[j]/sf;
    }
}

// ---------------------------------------------------------------------------
// Kernel 4: cat build in LDS + MFMA GEMM (split-bf16 hi/lo) + tanh.
// ---------------------------------------------------------------------------
#define STR 324
__global__ __launch_bounds__(256) void final_fused(
    const float* __restrict__ e, const float* __restrict__ f,
    const float* __restrict__ arrs, const float* __restrict__ att,
    const unsigned short* __restrict__ Wb1h, const unsigned short* __restrict__ Wb1l,
    const unsigned short* __restrict__ Wb2h, const unsigned short* __restrict__ Wb2l,
    const float* __restrict__ bv1, const float* __restrict__ bv2,
    float* __restrict__ out)
{
    __shared__ __align__(16) float cat_e[16*STR];
    __shared__ __align__(16) float cat_f[16*STR];

    int tid = threadIdx.x, lane = tid & 63, chunk = tid >> 6;
    int node0 = blockIdx.x * 16;

    #pragma unroll
    for (int round = 0; round < 4; ++round) {
        int ni = round*4 + chunk;
        int node = node0 + ni;
        int g = node / N_NODES;
        size_t idx = (size_t)node*FDIM + lane;
        float* ce = &cat_e[ni*STR];
        float* cf = &cat_f[ni*STR];
        ce[lane]     = arrs[0*NF + idx]*att[g*8+0];
        ce[64+lane]  = arrs[1*NF + idx]*att[g*8+1];
        ce[128+lane] = arrs[2*NF + idx]*att[g*8+2];
        ce[192+lane] = arrs[3*NF + idx]*att[g*8+3];
        ce[256+lane] = e[idx];
        cf[lane]     = arrs[4*NF + idx]*att[g*8+4];
        cf[64+lane]  = arrs[5*NF + idx]*att[g*8+5];
        cf[128+lane] = arrs[6*NF + idx]*att[g*8+6];
        cf[192+lane] = arrs[7*NF + idx]*att[g*8+7];
        cf[256+lane] = f[idx];
    }
    __syncthreads();

    float4v acc_e = {0.f, 0.f, 0.f, 0.f};
    float4v acc_f = {0.f, 0.f, 0.f, 0.f};
    int m16 = lane & 15, quad = lane >> 4;

    for (int ks = 0; ks < 10; ++ks) {
        const float* ar = &cat_e[m16*STR + ks*32 + quad*8];
        float4 a0 = *(const float4*)ar;
        float4 a1 = *(const float4*)(ar + 4);
        const float* br = &cat_f[m16*STR + ks*32 + quad*8];
        float4 c0 = *(const float4*)br;
        float4 c1 = *(const float4*)(br + 4);

        float av[8] = {a0.x,a0.y,a0.z,a0.w,a1.x,a1.y,a1.z,a1.w};
        float cv[8] = {c0.x,c0.y,c0.z,c0.w,c1.x,c1.y,c1.z,c1.w};
        short8 ah, al, ch, cl;
        #pragma unroll
        for (int j = 0; j < 8; ++j) {
            unsigned short h = f2bf(av[j]);
            ah[j] = (short)h; al[j] = (short)f2bf(av[j] - bf2f(h));
            unsigned short h2 = f2bf(cv[j]);
            ch[j] = (short)h2; cl[j] = (short)f2bf(cv[j] - bf2f(h2));
        }

        size_t boff = (size_t)((ks*4 + chunk)*64 + lane)*8;
        short8 b1h = *(const short8*)(Wb1h + boff);
        short8 b1l = *(const short8*)(Wb1l + boff);
        short8 b2h = *(const short8*)(Wb2h + boff);
        short8 b2l = *(const short8*)(Wb2l + boff);

        acc_e = __builtin_amdgcn_mfma_f32_16x16x32_bf16(ah, b1h, acc_e, 0, 0, 0);
        acc_e = __builtin_amdgcn_mfma_f32_16x16x32_bf16(al, b1h, acc_e, 0, 0, 0);
        acc_e = __builtin_amdgcn_mfma_f32_16x16x32_bf16(ah, b1l, acc_e, 0, 0, 0);
        acc_f = __builtin_amdgcn_mfma_f32_16x16x32_bf16(ch, b2h, acc_f, 0, 0, 0);
        acc_f = __builtin_amdgcn_mfma_f32_16x16x32_bf16(cl, b2h, acc_f, 0, 0, 0);
        acc_f = __builtin_amdgcn_mfma_f32_16x16x32_bf16(ch, b2l, acc_f, 0, 0, 0);
    }

    int o = chunk*16 + m16;
    float be = bv1[o], bf = bv2[o];
    #pragma unroll
    for (int reg = 0; reg < 4; ++reg) {
        int node = node0 + quad*4 + reg;
        out[(size_t)node*FDIM + o]      = tanhf(acc_e[reg] + be);
        out[NF + (size_t)node*FDIM + o] = tanhf(acc_f[reg] + bf);
    }
}

// ---------------------------------------------------------------------------
extern "C" void kernel_launch(void* const* d_in, const int* in_sizes, int n_in,
                              void* d_out, int out_size, void* d_ws, size_t ws_size,
                              hipStream_t stream) {
    (void)in_sizes; (void)n_in; (void)out_size; (void)ws_size;
    const float* e     = (const float*)d_in[0];
    const float* f     = (const float*)d_in[1];
    const int*   rowsG = (const int*)d_in[2];
    const int*   colsG = (const int*)d_in[3];
    const float* valsG = (const float*)d_in[4];
    const int*   rowsB = (const int*)d_in[5];
    const int*   colsB = (const int*)d_in[6];
    const float* valsB = (const float*)d_in[7];
    const int*   rows1 = (const int*)d_in[8];
    const int*   cols1 = (const int*)d_in[9];
    const float* vals1 = (const float*)d_in[10];
    const int*   rows2 = (const int*)d_in[11];
    const int*   cols2 = (const int*)d_in[12];
    const float* vals2 = (const float*)d_in[13];
    const float* G_d   = (const float*)d_in[14];
    const float* B_d   = (const float*)d_in[15];
    const float* Pd    = (const float*)d_in[16];
    const float* Qd    = (const float*)d_in[17];
    const float* W1    = (const float*)d_in[18];
    const float* b1    = (const float*)d_in[19];
    const float* W2    = (const float*)d_in[20];
    const float* b2    = (const float*)d_in[21];
    const float* w_ae  = (const float*)d_in[22];
    const float* b_ae  = (const float*)d_in[23];
    const float* w_af  = (const float*)d_in[24];
    const float* b_af  = (const float*)d_in[25];

    float* ws       = (float*)d_ws;
    float* arrs     = ws;                            // 8*NF
    float* partials = ws + 8*NF;                     // 128*22*8 = 22528
    float* att      = partials + 22528;              // 1024
    unsigned short* Wb1h = (unsigned short*)(att + 1024);  // 20480 shorts each
    unsigned short* Wb1l = Wb1h + 20480;
    unsigned short* Wb2h = Wb1l + 20480;
    unsigned short* Wb2l = Wb2h + 20480;
    int*   offs     = (int*)(Wb2l + 20480);          // 512*OSTR ints
    int2*  pairs    = (int2*)(offs + 512*OSTR);      // 512*EPG int2

    csr_build<<<dim3(592), dim3(256), 0, stream>>>(
        rowsG, colsG, valsG, rowsB, colsB, valsB,
        rows1, cols1, vals1, rows2, cols2, vals2,
        W1, W2, Wb1h, Wb1l, Wb2h, Wb2l, offs, pairs);

    gather_all<<<dim3(5632), dim3(256), 0, stream>>>(
        e, f, G_d, B_d, Pd, Qd, w_ae, w_af, offs, pairs, arrs, partials);

    attn_final<<<dim3(1), dim3(128), 0, stream>>>(partials, b_ae, b_af, att);

    final_fused<<<dim3(NTOT/16), dim3(256), 0, stream>>>(
        e, f, arrs, att, Wb1h, Wb1l, Wb2h, Wb2l, b1, b2, (float*)d_out);
}

// Round 7
// 406.921 us; speedup vs baseline: 1.2346x; 1.2346x over previous
//
#include <hip/hip_runtime.h>
#include <math.h>

#define N_NODES 661
#define N_GRAPH 128
#define DEG 8
#define EPG (N_NODES*DEG)          // 5288 edges per graph per matrix
#define NTOT (N_NODES*N_GRAPH)     // 84608 nodes
#define FDIM 64
#define NF ((size_t)NTOT*FDIM)     // elements per [n,64] array
#define OSTR 672                   // padded CSR offsets stride
#define NTILE 11
#define TROWS 61                   // 11*61 = 671 >= 661

using short8  = __attribute__((ext_vector_type(8))) short;
using float4v = __attribute__((ext_vector_type(4))) float;

__device__ __forceinline__ unsigned short f2bf(float x) {
    unsigned int u = __float_as_uint(x);
    unsigned int r = u + 0x7FFFu + ((u >> 16) & 1u);
    return (unsigned short)(r >> 16);
}
__device__ __forceinline__ float bf2f(unsigned short h) {
    return __uint_as_float(((unsigned int)h) << 16);
}
// pack float into (bf16_hi << 16) | bf16_lo residual
__device__ __forceinline__ unsigned pack_bf(float x) {
    unsigned short h = f2bf(x);
    unsigned short l = f2bf(x - bf2f(h));
    return ((unsigned)h << 16) | (unsigned)l;
}

// ---------------------------------------------------------------------------
// Kernel 1 (fused): blocks 0..511 -> per-(graph,matrix) LDS counting sort ->
// CSR; blocks 512..591 -> wtrans (bf16 hi/lo W fragments in MFMA B-layout).
// ---------------------------------------------------------------------------
__global__ __launch_bounds__(256) void csr_build(
    const int* __restrict__ rG, const int* __restrict__ cG, const float* __restrict__ vG,
    const int* __restrict__ rB, const int* __restrict__ cB, const float* __restrict__ vB,
    const int* __restrict__ r1, const int* __restrict__ c1, const float* __restrict__ v1,
    const int* __restrict__ r2, const int* __restrict__ c2, const float* __restrict__ v2,
    const float* __restrict__ W1, const float* __restrict__ W2,
    unsigned short* __restrict__ Wb1h, unsigned short* __restrict__ Wb1l,
    unsigned short* __restrict__ Wb2h, unsigned short* __restrict__ Wb2l,
    int* __restrict__ offs_out, int2* __restrict__ pairs_out)
{
    int bid = blockIdx.x;
    int tid = threadIdx.x;

    if (bid >= 512) {                     // ---- wtrans part ----
        int i = (bid - 512)*256 + tid;    // 0..20479
        int j    = i & 7;
        int lane = (i >> 3) & 63;
        int ot   = (i >> 9) & 3;
        int ks   = i >> 11;
        int k = ks*32 + (lane >> 4)*8 + j;
        int o = ot*16 + (lane & 15);
        float w1 = W1[o*320 + k];
        float w2 = W2[o*320 + k];
        unsigned short h1 = f2bf(w1); Wb1h[i] = h1; Wb1l[i] = f2bf(w1 - bf2f(h1));
        unsigned short h2 = f2bf(w2); Wb2h[i] = h2; Wb2l[i] = f2bf(w2 - bf2f(h2));
        return;
    }

    __shared__ int   scount[N_NODES];
    __shared__ int   soffs[N_NODES+1];
    __shared__ int   scursor[N_NODES];
    __shared__ int   scol[EPG];
    __shared__ float sval[EPG];
    __shared__ int   sscan[256];

    int g = bid & 127;
    int m = bid >> 7;
    const int*   rows = (m==0)?rG:(m==1)?rB:(m==2)?r1:r2;
    const int*   cols = (m==0)?cG:(m==1)?cB:(m==2)?c1:c2;
    const float* vals = (m==0)?vG:(m==1)?vB:(m==2)?v1:v2;

    int ebase = g*EPG;
    int gbase = g*N_NODES;
    int seg = m*N_GRAPH + g;

    for (int i = tid; i < N_NODES; i += 256) scount[i] = 0;
    __syncthreads();
    for (int i = tid; i < EPG; i += 256)
        atomicAdd(&scount[rows[ebase+i] - gbase], 1);
    __syncthreads();

    int c0 = tid*3;
    int ps = 0;
    #pragma unroll
    for (int j = 0; j < 3; ++j) { int i = c0+j; if (i < N_NODES) ps += scount[i]; }
    sscan[tid] = ps;
    __syncthreads();
    #pragma unroll
    for (int d = 1; d < 256; d <<= 1) {
        int v = (tid >= d) ? sscan[tid-d] : 0;
        __syncthreads();
        sscan[tid] += v;
        __syncthreads();
    }
    int run = sscan[tid] - ps;   // exclusive prefix
    #pragma unroll
    for (int j = 0; j < 3; ++j) {
        int i = c0+j;
        if (i < N_NODES) { soffs[i] = run; scursor[i] = run; run += scount[i]; }
    }
    if (tid == 0) soffs[N_NODES] = EPG;
    __syncthreads();

    for (int i = tid; i < EPG; i += 256) {
        int r = rows[ebase+i] - gbase;
        int pos = atomicAdd(&scursor[r], 1);
        scol[pos] = cols[ebase+i];
        sval[pos] = vals[ebase+i];
    }
    __syncthreads();

    for (int i = tid; i <= N_NODES; i += 256)
        offs_out[(size_t)seg*OSTR + i] = soffs[i];
    int2* po = pairs_out + (size_t)seg*EPG;
    for (int i = tid; i < EPG; i += 256)
        po[i] = make_int2(scol[i], __float_as_int(sval[i]));
}

// ---------------------------------------------------------------------------
__device__ __forceinline__ void node_math1(
    float ev, float fv, float gd, float bd, float pd, float qd,
    float eGv, float fGv, float eBv, float fBv,
    float& e3v, float& nev, float& f3v, float& nfv)
{
    float invb = 1.0f/(ev*ev + fv*fv + 0.1f);
    float alpha = (pd*ev + qd*fv)*invb - eGv - fBv;
    float beta  = (qd*ev - pd*fv)*invb + fGv + eBv;
    float invg = 1.0f/(gd*gd + bd*bd);
    e3v = (alpha*gd + beta*bd)*invg;
    f3v = (beta*gd - alpha*bd)*invg;
    float bb1 = eGv - fBv, bb2 = fGv + eBv;
    float vv = ev*ev + fv*fv;
    float P_ = pd - vv*gd, Q_ = qd + vv*bd;
    nev = (P_*bb1 + Q_*bb2)*invg;
    nfv = (P_*bb2 - Q_*bb1)*invg;
}

// ---------------------------------------------------------------------------
// Kernel 2: gather SpMM v3 (v1 skeleton). lane = feature (64x f32 gathers,
// 256 B/instr). A and B matrix batches interleaved -> 32 loads in flight,
// 2 waits per row. Pair indices wave-uniform (readfirstlane'd offsets).
// arrs written as packed bf16 hi|lo uints (MFMA-ready).
// arrs: [0]=e3 [1]=ne [2]=e1 [3]=e2 [4]=f3 [5]=nf [6]=f1 [7]=f2
// Grid: 2816 = 8 XCD * 16 graphs * 22 (11 tiles x 2 sets).
// ---------------------------------------------------------------------------
__global__ __launch_bounds__(256) void gather_all(
    const float* __restrict__ e, const float* __restrict__ f,
    const float* __restrict__ Gd, const float* __restrict__ Bd,
    const float* __restrict__ Pd, const float* __restrict__ Qd,
    const float* __restrict__ w_ae, const float* __restrict__ w_af,
    const int* __restrict__ offs, const int2* __restrict__ pairs,
    unsigned* __restrict__ arrs, float* __restrict__ partials)
{
    int tid = threadIdx.x, lane = tid & 63, wv = tid >> 6;
    int bid = blockIdx.x;
    int xcd = bid & 7, loc = bid >> 3;          // loc 0..351
    int g    = xcd*16 + loc/22;
    int sub  = loc % 22;
    int set  = (sub < NTILE) ? 0 : 1;
    int tile = sub - set*NTILE;
    int r0   = tile*TROWS;
    int rlim = min(TROWS, N_NODES - r0);
    int mA = set ? 2 : 0, mB = set ? 3 : 1;

    const int*  poA = offs + (size_t)(mA*N_GRAPH + g)*OSTR;
    const int*  poB = offs + (size_t)(mB*N_GRAPH + g)*OSTR;
    const int2* ppA = pairs + (size_t)(mA*N_GRAPH + g)*EPG;
    const int2* ppB = pairs + (size_t)(mB*N_GRAPH + g)*EPG;

    float wa = w_ae[lane], wf = w_af[lane];
    float pa0 = 0.f, pa1 = 0.f, pa2 = 0.f, pa3 = 0.f;

    for (int lr = wv; lr < rlim; lr += 4) {
        int r = r0 + lr;
        int node = g*N_NODES + r;
        int sA = __builtin_amdgcn_readfirstlane(poA[r]);
        int tA = __builtin_amdgcn_readfirstlane(poA[r+1]);
        int sB = __builtin_amdgcn_readfirstlane(poB[r]);
        int tB = __builtin_amdgcn_readfirstlane(poB[r+1]);
        int dA = tA - sA, dB = tB - sB;
        int nmax = max(dA, dB);

        float aE = 0.f, aF = 0.f, bE = 0.f, bF = 0.f;

        for (int base = 0; base < nmax; base += 8) {
            int2 pA[8], pB[8];
            #pragma unroll
            for (int j = 0; j < 8; ++j) {
                int k = base + j;
                int iA = (k < dA) ? (sA + k) : (sA ? sA - 1 : 0);
                int iB = (k < dB) ? (sB + k) : (sB ? sB - 1 : 0);
                pA[j] = ppA[iA];
                pB[j] = ppB[iB];
            }
            float evA[8], fvA[8], evB[8], fvB[8];
            #pragma unroll
            for (int j = 0; j < 8; ++j) {
                unsigned oA = ((unsigned)pA[j].x << 6) + (unsigned)lane;
                unsigned oB = ((unsigned)pB[j].x << 6) + (unsigned)lane;
                evA[j] = e[oA]; fvA[j] = f[oA];
                evB[j] = e[oB]; fvB[j] = f[oB];
            }
            #pragma unroll
            for (int j = 0; j < 8; ++j) {
                int k = base + j;
                float vA = (k < dA) ? __int_as_float(pA[j].y) : 0.f;
                float vB = (k < dB) ? __int_as_float(pB[j].y) : 0.f;
                aE = fmaf(vA, evA[j], aE); aF = fmaf(vA, fvA[j], aF);
                bE = fmaf(vB, evB[j], bE); bF = fmaf(vB, fvB[j], bF);
            }
        }

        size_t idx = (size_t)node*FDIM + lane;
        if (set == 0) {
            float ev = e[idx], fv = f[idx];
            float gd = Gd[node], bd = Bd[node], pd = Pd[node], qd = Qd[node];
            float e3v, nev, f3v, nfv;
            node_math1(ev, fv, gd, bd, pd, qd, aE, aF, bE, bF, e3v, nev, f3v, nfv);
            arrs[0*NF + idx] = pack_bf(e3v);
            arrs[1*NF + idx] = pack_bf(nev);
            arrs[4*NF + idx] = pack_bf(f3v);
            arrs[5*NF + idx] = pack_bf(nfv);
            pa0 += e3v*wa; pa1 += nev*wa; pa2 += f3v*wf; pa3 += nfv*wf;
        } else {
            arrs[2*NF + idx] = pack_bf(aE);   // e1
            arrs[3*NF + idx] = pack_bf(bE);   // e2
            arrs[6*NF + idx] = pack_bf(aF);   // f1
            arrs[7*NF + idx] = pack_bf(bF);   // f2
            pa0 += aE*wa; pa1 += bE*wa; pa2 += aF*wf; pa3 += bF*wf;
        }
    }

    __shared__ float sred[4];
    if (tid < 4) sred[tid] = 0.f;
    __syncthreads();
    #pragma unroll
    for (int off = 32; off > 0; off >>= 1) {
        pa0 += __shfl_down(pa0, off); pa1 += __shfl_down(pa1, off);
        pa2 += __shfl_down(pa2, off); pa3 += __shfl_down(pa3, off);
    }
    if (lane == 0) {
        atomicAdd(&sred[0], pa0); atomicAdd(&sred[1], pa1);
        atomicAdd(&sred[2], pa2); atomicAdd(&sred[3], pa3);
    }
    __syncthreads();
    if (tid == 0) {
        float* pt = partials + ((size_t)g*NTILE + tile)*8;
        if (set == 0) { pt[0] = sred[0]; pt[1] = sred[1]; pt[4] = sred[2]; pt[5] = sred[3]; }
        else          { pt[2] = sred[0]; pt[3] = sred[1]; pt[6] = sred[2]; pt[7] = sred[3]; }
    }
}

// ---------------------------------------------------------------------------
// Kernel 3: finalize attention weights
// ---------------------------------------------------------------------------
__global__ void attn_final(const float* __restrict__ partials,
                           const float* __restrict__ b_ae, const float* __restrict__ b_af,
                           float* __restrict__ att)
{
    int g = threadIdx.x;
    if (g >= N_GRAPH) return;
    float s[8];
    #pragma unroll
    for (int j = 0; j < 8; ++j) {
        float t = 0.f;
        for (int q = 0; q < NTILE; ++q) t += partials[((size_t)g*NTILE + q)*8 + j];
        s[j] = t;
    }
    float ae[4], af[4], se = 1e-4f, sf = 1e-4f;
    float bae = b_ae[0], baf = b_af[0];
    #pragma unroll
    for (int j = 0; j < 4; ++j) {
        float x = s[j]*(1.0f/N_NODES) + bae;
        ae[j] = 1.0f/(1.0f + expf(-x)); se += ae[j];
        float y = s[4+j]*(1.0f/N_NODES) + baf;
        af[j] = 1.0f/(1.0f + expf(-y)); sf += af[j];
    }
    #pragma unroll
    for (int j = 0; j < 4; ++j) {
        att[g*8 + j]     = ae[j]/se;
        att[g*8 + 4 + j] = af[j]/sf;
    }
}

// ---------------------------------------------------------------------------
// Kernel 4: MFMA epilogue. Stage packed-bf16 uints into LDS in fragment
// order (10 segs: e3,ne,e1,e2,e | f3,nf,f1,f2,f), unpack hi/lo with shifts,
// 5 per-segment accumulators, att folded post-MFMA, tanh + store.
// LDS slot layout: [seg*8 + (feat>>3)][node 0..15][8 elems], stride 132.
// ---------------------------------------------------------------------------
__global__ __launch_bounds__(256) void final_fused(
    const float* __restrict__ e, const float* __restrict__ f,
    const unsigned* __restrict__ arrs, const float* __restrict__ att,
    const unsigned short* __restrict__ Wb1h, const unsigned short* __restrict__ Wb1l,
    const unsigned short* __restrict__ Wb2h, const unsigned short* __restrict__ Wb2l,
    const float* __restrict__ bv1, const float* __restrict__ bv2,
    float* __restrict__ out)
{
    __shared__ __align__(16) unsigned sfrag[80*132];

    int tid = threadIdx.x, lane = tid & 63, chunk = tid >> 6;
    int node0 = blockIdx.x * 16;
    int sl = lane >> 3, jj = lane & 7;

    #pragma unroll
    for (int round = 0; round < 4; ++round) {
        int ni = round*4 + chunk;
        size_t idx = (size_t)(node0 + ni)*FDIM + lane;
        #pragma unroll
        for (int seg = 0; seg < 10; ++seg) {
            unsigned u;
            if (seg == 4)      u = pack_bf(e[idx]);
            else if (seg == 9) u = pack_bf(f[idx]);
            else {
                int a = (seg < 4) ? seg : seg - 1;   // segs 0..3 -> arrs0..3; 5..8 -> arrs4..7
                u = arrs[(size_t)a*NF + idx];
            }
            sfrag[(seg*8 + sl)*132 + ni*8 + jj] = u;
        }
    }
    __syncthreads();

    int m16 = lane & 15, quad = lane >> 4;
    float4v acce[5], accf[5];
    #pragma unroll
    for (int s = 0; s < 5; ++s) {
        acce[s] = (float4v){0.f,0.f,0.f,0.f};
        accf[s] = (float4v){0.f,0.f,0.f,0.f};
    }

    #pragma unroll
    for (int seg = 0; seg < 5; ++seg) {
        #pragma unroll
        for (int ks2 = 0; ks2 < 2; ++ks2) {
            int ks = seg*2 + ks2;
            size_t boff = (size_t)((ks*4 + chunk)*64 + lane)*8;
            // e-side
            {
                const unsigned* pa = &sfrag[(seg*8 + ks2*4 + quad)*132 + m16*8];
                uint4 ua = *(const uint4*)pa;
                uint4 ub = *(const uint4*)(pa + 4);
                unsigned uu[8] = {ua.x,ua.y,ua.z,ua.w,ub.x,ub.y,ub.z,ub.w};
                short8 ah, al;
                #pragma unroll
                for (int j = 0; j < 8; ++j) {
                    ah[j] = (short)(uu[j] >> 16);
                    al[j] = (short)(uu[j] & 0xFFFFu);
                }
                short8 bh = *(const short8*)(Wb1h + boff);
                short8 bl = *(const short8*)(Wb1l + boff);
                acce[seg] = __builtin_amdgcn_mfma_f32_16x16x32_bf16(ah, bh, acce[seg], 0, 0, 0);
                acce[seg] = __builtin_amdgcn_mfma_f32_16x16x32_bf16(al, bh, acce[seg], 0, 0, 0);
                acce[seg] = __builtin_amdgcn_mfma_f32_16x16x32_bf16(ah, bl, acce[seg], 0, 0, 0);
            }
            // f-side
            {
                const unsigned* pa = &sfrag[((seg+5)*8 + ks2*4 + quad)*132 + m16*8];
                uint4 ua = *(const uint4*)pa;
                uint4 ub = *(const uint4*)(pa + 4);
                unsigned uu[8] = {ua.x,ua.y,ua.z,ua.w,ub.x,ub.y,ub.z,ub.w};
                short8 ch, cl;
                #pragma unroll
                for (int j = 0; j < 8; ++j) {
                    ch[j] = (short)(uu[j] >> 16);
                    cl[j] = (short)(uu[j] & 0xFFFFu);
                }
                short8 bh = *(const short8*)(Wb2h + boff);
                short8 bl = *(const short8*)(Wb2l + boff);
                accf[seg] = __builtin_amdgcn_mfma_f32_16x16x32_bf16(ch, bh, accf[seg], 0, 0, 0);
                accf[seg] = __builtin_amdgcn_mfma_f32_16x16x32_bf16(cl, bh, accf[seg], 0, 0, 0);
                accf[seg] = __builtin_amdgcn_mfma_f32_16x16x32_bf16(ch, bl, accf[seg], 0, 0, 0);
            }
        }
    }

    int o = chunk*16 + m16;
    float be = bv1[o], bf = bv2[o];
    #pragma unroll
    for (int reg = 0; reg < 4; ++reg) {
        int node = node0 + quad*4 + reg;
        int g = node / N_NODES;
        float se2 = acce[4][reg];
        float sf2 = accf[4][reg];
        #pragma unroll
        for (int b = 0; b < 4; ++b) {
            se2 = fmaf(att[g*8 + b],     acce[b][reg], se2);
            sf2 = fmaf(att[g*8 + 4 + b], accf[b][reg], sf2);
        }
        out[(size_t)node*FDIM + o]      = tanhf(se2 + be);
        out[NF + (size_t)node*FDIM + o] = tanhf(sf2 + bf);
    }
}

// ---------------------------------------------------------------------------
extern "C" void kernel_launch(void* const* d_in, const int* in_sizes, int n_in,
                              void* d_out, int out_size, void* d_ws, size_t ws_size,
                              hipStream_t stream) {
    (void)in_sizes; (void)n_in; (void)out_size; (void)ws_size;
    const float* e     = (const float*)d_in[0];
    const float* f     = (const float*)d_in[1];
    const int*   rowsG = (const int*)d_in[2];
    const int*   colsG = (const int*)d_in[3];
    const float* valsG = (const float*)d_in[4];
    const int*   rowsB = (const int*)d_in[5];
    const int*   colsB = (const int*)d_in[6];
    const float* valsB = (const float*)d_in[7];
    const int*   rows1 = (const int*)d_in[8];
    const int*   cols1 = (const int*)d_in[9];
    const float* vals1 = (const float*)d_in[10];
    const int*   rows2 = (const int*)d_in[11];
    const int*   cols2 = (const int*)d_in[12];
    const float* vals2 = (const float*)d_in[13];
    const float* G_d   = (const float*)d_in[14];
    const float* B_d   = (const float*)d_in[15];
    const float* Pd    = (const float*)d_in[16];
    const float* Qd    = (const float*)d_in[17];
    const float* W1    = (const float*)d_in[18];
    const float* b1    = (const float*)d_in[19];
    const float* W2    = (const float*)d_in[20];
    const float* b2    = (const float*)d_in[21];
    const float* w_ae  = (const float*)d_in[22];
    const float* b_ae  = (const float*)d_in[23];
    const float* w_af  = (const float*)d_in[24];
    const float* b_af  = (const float*)d_in[25];

    unsigned* arrs  = (unsigned*)d_ws;               // 8*NF uints (packed bf16 h|l)
    float* partials = (float*)(arrs + 8*NF);         // 128*11*8 = 11264
    float* att      = partials + 11264;              // 1024
    unsigned short* Wb1h = (unsigned short*)(att + 1024);  // 20480 shorts each
    unsigned short* Wb1l = Wb1h + 20480;
    unsigned short* Wb2h = Wb1l + 20480;
    unsigned short* Wb2l = Wb2h + 20480;
    int*   offs     = (int*)(Wb2l + 20480);          // 512*OSTR ints
    int2*  pairs    = (int2*)(offs + 512*OSTR);      // 512*EPG int2

    csr_build<<<dim3(592), dim3(256), 0, stream>>>(
        rowsG, colsG, valsG, rowsB, colsB, valsB,
        rows1, cols1, vals1, rows2, cols2, vals2,
        W1, W2, Wb1h, Wb1l, Wb2h, Wb2l, offs, pairs);

    gather_all<<<dim3(2816), dim3(256), 0, stream>>>(
        e, f, G_d, B_d, Pd, Qd, w_ae, w_af, offs, pairs, arrs, partials);

    attn_final<<<dim3(1), dim3(128), 0, stream>>>(partials, b_ae, b_af, att);

    final_fused<<<dim3(NTOT/16), dim3(256), 0, stream>>>(
        e, f, arrs, att, Wb1h, Wb1l, Wb2h, Wb2l, b1, b2, (float*)d_out);
}